// Round 6
// baseline (261.864 us; speedup 1.0000x reference)
//
#include <hip/hip_runtime.h>

#define BS     8192
#define DIM    768
#define NPART  16
#define BM     128
#define BN     128
#define BKB    128              // K-tile in fp8 bytes
#define PCOLS  (BS / NPART)     // 512 cols per partition
#define NJT    (PCOLS / BN)     // 4 col-tiles per block
#define NKT    (DIM / BKB)      // 6 k-tiles
#define NEL    ((size_t)BS * DIM)        // 6291456
#define NEL4   (NEL / 4)                 // 1572864 float4 tiles per input
#define CTILE  (2 * NEL4 - 1)            // dst float4 tiles: m in [1, 3145727]
#define SCL1   0x7F7F7F7F                // e8m0 = 127 -> scale 1.0 in every byte

typedef float facc_t __attribute__((ext_vector_type(4)));
typedef int   iv8    __attribute__((ext_vector_type(8)));

typedef const __attribute__((address_space(1))) void gv_t;
typedef __attribute__((address_space(3))) void lv_t;

__device__ __forceinline__ void gll16(const void* g, void* l) {
  // async global->LDS DMA, 16B/lane; LDS dest = wave-uniform base + lane*16
  __builtin_amdgcn_global_load_lds((gv_t*)g, (lv_t*)l, 16, 0, 0);
}

// pack float4 -> 4x fp8 e4m3 (OCP on gfx950)
__device__ __forceinline__ int pk_fp8(float4 v) {
  int w = __builtin_amdgcn_cvt_pk_fp8_f32(v.x, v.y, 0, false);
  w = __builtin_amdgcn_cvt_pk_fp8_f32(v.z, v.w, w, true);
  return w;
}

// ---------------- prep: fp8 convert (both inputs) + fp32 diag ----------------
__global__ void prep_kernel(const float* __restrict__ nl, const float* __restrict__ cd,
                            unsigned char* __restrict__ nl8, unsigned char* __restrict__ cd8,
                            float* __restrict__ dg) {
  const int lane = threadIdx.x & 63;
  const int wave = threadIdx.x >> 6;
  const int row  = blockIdx.x * 4 + wave;
  const size_t rbase = (size_t)row * DIM;
  const float4* ar = reinterpret_cast<const float4*>(nl + rbase);
  const float4* br = reinterpret_cast<const float4*>(cd + rbase);
  int* ba = reinterpret_cast<int*>(nl8 + rbase);   // 4 fp8 per int
  int* bb = reinterpret_cast<int*>(cd8 + rbase);

  float s = 0.f;
#pragma unroll
  for (int i = 0; i < 3; ++i) {                 // 192 float4 per row, 3 per lane
    int idx = lane + 64 * i;
    float4 x = ar[idx];
    float4 y = br[idx];
    ba[idx] = pk_fp8(x);
    bb[idx] = pk_fp8(y);
    s += x.x * y.x + x.y * y.y + x.z * y.z + x.w * y.w;
  }
#pragma unroll
  for (int off = 32; off; off >>= 1) s += __shfl_xor(s, off, 64);
  if (lane == 0) dg[row] = s;
}

// concat source: tile i of [cd | nl] as float4
__device__ __forceinline__ float4 cc4(const float4* cd4, const float4* nl4, size_t i) {
  return (i < NEL4) ? cd4[i] : nl4[i - NEL4];
}

// ---------------- fused GEMM (MX-fp8 MFMA, scales=1) + online lse + output copy ----------------
// block: 256 threads (4 waves, 2x2 of 64x64), tile 128x128, BK=128 fp8 bytes.
// grid: (NPART, BS/BM) = (16, 64) = 1024 blocks.
// LDS: XOR-swizzled, unpadded: 16B unit at position p of row r holds global unit p^(r&7).
// A-fragment (16x16x128 f8f6f4): row = lane&15, k = (lane>>4)*32 + j (32 contiguous bytes).
__global__ __launch_bounds__(256, 4) void gemm_lse_kernel(
    const unsigned char* __restrict__ A8,
    const unsigned char* __restrict__ B8,
    const float* __restrict__ cdf, const float* __restrict__ nlf,
    float* __restrict__ outp,
    float* __restrict__ pm, float* __restrict__ pl) {
  __shared__ __align__(16) unsigned char As[BM * BKB];   // 16 KB
  __shared__ __align__(16) unsigned char Bs[BN * BKB];   // 16 KB

  const int tid  = threadIdx.x;
  const int lane = tid & 63;
  const int wave = tid >> 6;
  const int wm   = wave >> 1;
  const int wn   = wave & 1;
  const int l15  = lane & 15;
  const int l4   = lane >> 4;
  const int sw   = l15 & 7;        // row-dependent xor for fragment reads
  const int kb2  = l4 * 2;         // first 16B logical unit of this lane's 32B k-block
  const int cp   = blockIdx.x;
  const int rb   = blockIdx.y;

  // ---- output copy prologue (dst 16B-aligned; out[4m..4m+3] = concat[4m-1..4m+2]) ----
  {
    const float4* cd4 = reinterpret_cast<const float4*>(cdf);
    const float4* nl4 = reinterpret_cast<const float4*>(nlf);
    const size_t gtid = ((size_t)blockIdx.y * gridDim.x + blockIdx.x) * blockDim.x + tid;
    const size_t nthr = (size_t)gridDim.x * gridDim.y * blockDim.x;   // 262144
    for (size_t m = 1 + gtid; m <= CTILE; m += nthr) {
      float4 A = cc4(cd4, nl4, m - 1);
      float4 B = cc4(cd4, nl4, m);
      float4 d;
      d.x = A.w; d.y = B.x; d.z = B.y; d.w = B.z;
      *reinterpret_cast<float4*>(outp + 4 * m) = d;
    }
    if (gtid == 0) {
      outp[0] = 0.f;                       // loss accumulator (loss kernel atomically adds)
      outp[1] = cdf[0]; outp[2] = cdf[1]; outp[3] = cdf[2];
      outp[2 * NEL] = nlf[NEL - 1];        // last element
    }
  }

  // staging geometry (kt-invariant): unit u = wave*256 + t*64 + lane, 8 units/row
  int srow[4], sc8g[4];
#pragma unroll
  for (int t = 0; t < 4; ++t) {
    int u   = wave * 256 + t * 64 + lane;
    srow[t] = u >> 3;
    sc8g[t] = (u & 7) ^ (srow[t] & 7);
  }

  float mrun[4][4], lrun[4][4];
#pragma unroll
  for (int i = 0; i < 4; ++i)
#pragma unroll
    for (int r = 0; r < 4; ++r) { mrun[i][r] = -1e30f; lrun[i][r] = 0.f; }

  for (int jt = 0; jt < NJT; ++jt) {
    facc_t acc[4][4];
#pragma unroll
    for (int mt = 0; mt < 4; ++mt)
#pragma unroll
      for (int nt = 0; nt < 4; ++nt) acc[mt][nt] = (facc_t){0.f, 0.f, 0.f, 0.f};

    for (int kt = 0; kt < NKT; ++kt) {
      __syncthreads();
#pragma unroll
      for (int t = 0; t < 4; ++t) {
        int ub = (wave * 256 + t * 64) * 16;   // LDS byte base (lane adds lane*16)
        gll16(A8 + (size_t)(rb * BM + srow[t]) * DIM + kt * BKB + sc8g[t] * 16, As + ub);
        gll16(B8 + (size_t)(cp * PCOLS + jt * BN + srow[t]) * DIM + kt * BKB + sc8g[t] * 16, Bs + ub);
      }
      __syncthreads();

      // B fragments first (kept live), then stream A fragments
      iv8 bfv[4];
#pragma unroll
      for (int nt = 0; nt < 4; ++nt) {
        const unsigned char* base = &Bs[(wn * 64 + nt * 16 + l15) * BKB];
        int4 lo = *reinterpret_cast<const int4*>(base + ((kb2    ) ^ sw) * 16);
        int4 hi = *reinterpret_cast<const int4*>(base + ((kb2 + 1) ^ sw) * 16);
        iv8 b; b[0]=lo.x; b[1]=lo.y; b[2]=lo.z; b[3]=lo.w; b[4]=hi.x; b[5]=hi.y; b[6]=hi.z; b[7]=hi.w;
        bfv[nt] = b;
      }
#pragma unroll
      for (int mt = 0; mt < 4; ++mt) {
        const unsigned char* base = &As[(wm * 64 + mt * 16 + l15) * BKB];
        int4 lo = *reinterpret_cast<const int4*>(base + ((kb2    ) ^ sw) * 16);
        int4 hi = *reinterpret_cast<const int4*>(base + ((kb2 + 1) ^ sw) * 16);
        iv8 av; av[0]=lo.x; av[1]=lo.y; av[2]=lo.z; av[3]=lo.w; av[4]=hi.x; av[5]=hi.y; av[6]=hi.z; av[7]=hi.w;
#pragma unroll
        for (int nt = 0; nt < 4; ++nt)
          acc[mt][nt] = __builtin_amdgcn_mfma_scale_f32_16x16x128_f8f6f4(
              av, bfv[nt], acc[mt][nt], 0, 0, 0, SCL1, 0, SCL1);
      }
    }

    // online-lse update (per lane over its own column subset)
#pragma unroll
    for (int mt = 0; mt < 4; ++mt)
#pragma unroll
      for (int r = 0; r < 4; ++r) {
        float v0 = acc[mt][0][r], v1 = acc[mt][1][r], v2 = acc[mt][2][r], v3 = acc[mt][3][r];
        float tm = fmaxf(fmaxf(v0, v1), fmaxf(v2, v3));
        float mn = fmaxf(mrun[mt][r], tm);
        float sc = __expf(mrun[mt][r] - mn);
        lrun[mt][r] = lrun[mt][r] * sc +
                      __expf(v0 - mn) + __expf(v1 - mn) + __expf(v2 - mn) + __expf(v3 - mn);
        mrun[mt][r] = mn;
      }
  }

  // merge across the 16 lanes sharing rows (different column subsets)
#pragma unroll
  for (int mask = 1; mask < 16; mask <<= 1)
#pragma unroll
    for (int mt = 0; mt < 4; ++mt)
#pragma unroll
      for (int r = 0; r < 4; ++r) {
        float om = __shfl_xor(mrun[mt][r], mask, 64);
        float ol = __shfl_xor(lrun[mt][r], mask, 64);
        float mn = fmaxf(mrun[mt][r], om);
        lrun[mt][r] = lrun[mt][r] * __expf(mrun[mt][r] - mn) + ol * __expf(om - mn);
        mrun[mt][r] = mn;
      }

  // combine the two column-half waves via LDS (alias onto As/Bs — done with tiles)
  float* cm = reinterpret_cast<float*>(As);   // [2][BM]
  float* cl = reinterpret_cast<float*>(Bs);   // [2][BM]
  __syncthreads();
  if (l15 == 0) {
#pragma unroll
    for (int mt = 0; mt < 4; ++mt)
#pragma unroll
      for (int r = 0; r < 4; ++r) {
        int rl = wm * 64 + mt * 16 + l4 * 4 + r;
        cm[wn * BM + rl] = mrun[mt][r];
        cl[wn * BM + rl] = lrun[mt][r];
      }
  }
  __syncthreads();
  if (tid < BM) {
    float m0 = cm[tid], l0 = cl[tid];
    float m1 = cm[BM + tid], l1 = cl[BM + tid];
    float mn = fmaxf(m0, m1);
    float ll = l0 * __expf(m0 - mn) + l1 * __expf(m1 - mn);
    size_t g = (size_t)(rb * BM + tid) * NPART + cp;
    pm[g] = mn;
    pl[g] = ll;
  }
}

// ---------------- loss: combine partitions, subtract diag, atomic mean ----------------
__global__ void loss_kernel(const float* __restrict__ pm, const float* __restrict__ pl,
                            const float* __restrict__ dg, float* __restrict__ out) {
  __shared__ float red[4];
  const int tid = threadIdx.x;
  const int r   = blockIdx.x * 256 + tid;

  const float4* pmr = reinterpret_cast<const float4*>(pm + (size_t)r * NPART);
  const float4* plr = reinterpret_cast<const float4*>(pl + (size_t)r * NPART);

  float m = -1e30f, l = 0.f;
#pragma unroll
  for (int q = 0; q < NPART / 4; ++q) {
    float4 mv = pmr[q];
    float4 lv = plr[q];
#pragma unroll
    for (int k = 0; k < 4; ++k) {
      float m2 = (&mv.x)[k], l2 = (&lv.x)[k];
      float mn = fmaxf(m, m2);
      l = l * __expf(m - mn) + l2 * __expf(m2 - mn);
      m = mn;
    }
  }
  float local = m + __logf(l) - dg[r];

#pragma unroll
  for (int off = 32; off; off >>= 1) local += __shfl_xor(local, off, 64);
  if ((tid & 63) == 0) red[tid >> 6] = local;
  __syncthreads();
  if (tid == 0) {
    float s = red[0] + red[1] + red[2] + red[3];
    atomicAdd(out, s / (float)BS);
  }
}

extern "C" void kernel_launch(void* const* d_in, const int* in_sizes, int n_in,
                              void* d_out, int out_size, void* d_ws, size_t ws_size,
                              hipStream_t stream) {
  const float* nl = (const float*)d_in[0];
  const float* cd = (const float*)d_in[1];
  float* out = (float*)d_out;

  unsigned char* nl8 = (unsigned char*)d_ws;         // NEL fp8
  unsigned char* cd8 = nl8 + NEL;                    // NEL fp8
  float* pm = (float*)(cd8 + NEL);                   // BS*NPART
  float* pl = pm + (size_t)BS * NPART;               // BS*NPART
  float* dg = pl + (size_t)BS * NPART;               // BS

  // out = [loss, code_vec copy, nl_vec copy]; copies + out[0]=0 done in gemm prologue
  prep_kernel<<<BS / 4, 256, 0, stream>>>(nl, cd, nl8, cd8, dg);
  gemm_lse_kernel<<<dim3(NPART, BS / BM), 256, 0, stream>>>(nl8, cd8, cd, nl, out, pm, pl);
  loss_kernel<<<BS / 256, 256, 0, stream>>>(pm, pl, dg, out);
}

// Round 7
// 231.136 us; speedup vs baseline: 1.1329x; 1.1329x over previous
//
#include <hip/hip_runtime.h>

#define BS     8192
#define DIM    768
#define NPART  64               // 128-column partitions
#define BM     128
#define BN     128
#define BKB    128              // K-tile in fp8 bytes
#define NKT    (DIM / BKB)      // 6 k-tiles
#define NEL    ((size_t)BS * DIM)        // 6291456
#define NEL4   (NEL / 4)                 // 1572864 float4 tiles per input
#define CTILE  (2 * NEL4 - 1)            // dst float4 tiles: m in [1, 3145727]
#define SCL1   0x7F7F7F7F                // e8m0 = 127 -> scale 1.0 in every byte

typedef float facc_t __attribute__((ext_vector_type(4)));
typedef int   iv8    __attribute__((ext_vector_type(8)));

typedef const __attribute__((address_space(1))) void gv_t;
typedef __attribute__((address_space(3))) void lv_t;

__device__ __forceinline__ void gll16(const void* g, void* l) {
  // async global->LDS DMA, 16B/lane; LDS dest = wave-uniform base + lane*16
  __builtin_amdgcn_global_load_lds((gv_t*)g, (lv_t*)l, 16, 0, 0);
}

// build 8xi32 MFMA operand from two aligned 16B LDS units -> 2x ds_read_b128
__device__ __forceinline__ iv8 ld_frag(const int4* base, int lo, int hi) {
  union { iv8 v; int4 h[2]; } u;
  u.h[0] = base[lo];
  u.h[1] = base[hi];
  return u.v;
}

// pack float4 -> 4x fp8 e4m3 (OCP on gfx950)
__device__ __forceinline__ int pk_fp8(float4 v) {
  int w = __builtin_amdgcn_cvt_pk_fp8_f32(v.x, v.y, 0, false);
  w = __builtin_amdgcn_cvt_pk_fp8_f32(v.z, v.w, w, true);
  return w;
}

// ---------------- prep: fp8 convert (both inputs) + fp32 diag ----------------
__global__ void prep_kernel(const float* __restrict__ nl, const float* __restrict__ cd,
                            unsigned char* __restrict__ nl8, unsigned char* __restrict__ cd8,
                            float* __restrict__ dg) {
  const int lane = threadIdx.x & 63;
  const int wave = threadIdx.x >> 6;
  const int row  = blockIdx.x * 4 + wave;
  const size_t rbase = (size_t)row * DIM;
  const float4* ar = reinterpret_cast<const float4*>(nl + rbase);
  const float4* br = reinterpret_cast<const float4*>(cd + rbase);
  int* ba = reinterpret_cast<int*>(nl8 + rbase);   // 4 fp8 per int
  int* bb = reinterpret_cast<int*>(cd8 + rbase);

  float s = 0.f;
#pragma unroll
  for (int i = 0; i < 3; ++i) {                 // 192 float4 per row, 3 per lane
    int idx = lane + 64 * i;
    float4 x = ar[idx];
    float4 y = br[idx];
    ba[idx] = pk_fp8(x);
    bb[idx] = pk_fp8(y);
    s += x.x * y.x + x.y * y.y + x.z * y.z + x.w * y.w;
  }
#pragma unroll
  for (int off = 32; off; off >>= 1) s += __shfl_xor(s, off, 64);
  if (lane == 0) dg[row] = s;
}

// concat source: tile i of [cd | nl] as float4
__device__ __forceinline__ float4 cc4(const float4* cd4, const float4* nl4, size_t i) {
  return (i < NEL4) ? cd4[i] : nl4[i - NEL4];
}

// ---------------- fused GEMM (MX-fp8 MFMA, scales=1) + lse + output copy ----------------
// block: 256 threads (4 waves, 2x2 of 64x64), tile 128x128, one col-partition per block.
// grid: (NPART, BS/BM) = (64, 64) = 4096 blocks.
// LDS int4-typed, XOR-swizzled: 16B unit at position p of row r holds logical unit p^(r&7).
__global__ __launch_bounds__(256, 4) void gemm_lse_kernel(
    const unsigned char* __restrict__ A8,
    const unsigned char* __restrict__ B8,
    const float* __restrict__ cdf, const float* __restrict__ nlf,
    float* __restrict__ outp,
    float* __restrict__ pm, float* __restrict__ pl) {
  __shared__ int4 As4[BM * 8];   // 16 KB, 8 units of 16B per 128B row
  __shared__ int4 Bs4[BN * 8];   // 16 KB

  const int tid  = threadIdx.x;
  const int lane = tid & 63;
  const int wave = tid >> 6;
  const int wm   = wave >> 1;
  const int wn   = wave & 1;
  const int l15  = lane & 15;
  const int l4   = lane >> 4;
  const int sw   = l15 & 7;        // row-dependent xor for fragment reads
  const int kb2  = l4 * 2;         // lane's first 16B logical unit (32B k-block)
  const int cp   = blockIdx.x;
  const int rb   = blockIdx.y;

  // ---- output copy prologue (dst 16B-aligned; out[4m..4m+3] = concat[4m-1..4m+2]) ----
  {
    const float4* cd4 = reinterpret_cast<const float4*>(cdf);
    const float4* nl4 = reinterpret_cast<const float4*>(nlf);
    const size_t gtid = ((size_t)blockIdx.y * gridDim.x + blockIdx.x) * blockDim.x + tid;
    const size_t nthr = (size_t)gridDim.x * gridDim.y * blockDim.x;   // 1048576
    for (size_t m = 1 + gtid; m <= CTILE; m += nthr) {
      float4 A = cc4(cd4, nl4, m - 1);
      float4 B = cc4(cd4, nl4, m);
      float4 d;
      d.x = A.w; d.y = B.x; d.z = B.y; d.w = B.z;
      *reinterpret_cast<float4*>(outp + 4 * m) = d;
    }
    if (gtid == 0) {
      outp[0] = 0.f;                       // loss accumulator (loss kernel atomically adds)
      outp[1] = cdf[0]; outp[2] = cdf[1]; outp[3] = cdf[2];
      outp[2 * NEL] = nlf[NEL - 1];        // last element
    }
  }

  // staging geometry (kt-invariant): unit u = wave*256 + t*64 + lane, 8 units/row
  int srow[4], sc8g[4];
#pragma unroll
  for (int t = 0; t < 4; ++t) {
    int u   = wave * 256 + t * 64 + lane;
    srow[t] = u >> 3;
    sc8g[t] = (u & 7) ^ (srow[t] & 7);
  }

  facc_t acc[4][4];
#pragma unroll
  for (int mt = 0; mt < 4; ++mt)
#pragma unroll
    for (int nt = 0; nt < 4; ++nt) acc[mt][nt] = (facc_t){0.f, 0.f, 0.f, 0.f};

  for (int kt = 0; kt < NKT; ++kt) {
    __syncthreads();
#pragma unroll
    for (int t = 0; t < 4; ++t) {
      int ub = (wave * 256 + t * 64) * 16;   // LDS byte base (lane adds lane*16)
      gll16(A8 + (size_t)(rb * BM + srow[t]) * DIM + kt * BKB + sc8g[t] * 16,
            reinterpret_cast<char*>(As4) + ub);
      gll16(B8 + (size_t)(cp * BN + srow[t]) * DIM + kt * BKB + sc8g[t] * 16,
            reinterpret_cast<char*>(Bs4) + ub);
    }
    __syncthreads();

    const int lo = kb2 ^ sw, hi = (kb2 + 1) ^ sw;
    // cache A fragments (32 VGPRs), stream B fragments one at a time (8 VGPRs)
    iv8 af[4];
#pragma unroll
    for (int mt = 0; mt < 4; ++mt)
      af[mt] = ld_frag(&As4[(wm * 64 + mt * 16 + l15) * 8], lo, hi);
#pragma unroll
    for (int nt = 0; nt < 4; ++nt) {
      iv8 bf = ld_frag(&Bs4[(wn * 64 + nt * 16 + l15) * 8], lo, hi);
#pragma unroll
      for (int mt = 0; mt < 4; ++mt)
        acc[mt][nt] = __builtin_amdgcn_mfma_scale_f32_16x16x128_f8f6f4(
            af[mt], bf, acc[mt][nt], 0, 0, 0, SCL1, 0, SCL1);
    }
  }

  // ---- lse over this block's 128 columns (no running state needed: one col-slice) ----
  float mv[4][4], lv[4][4];
#pragma unroll
  for (int mt = 0; mt < 4; ++mt)
#pragma unroll
    for (int r = 0; r < 4; ++r) {
      float v0 = acc[mt][0][r], v1 = acc[mt][1][r], v2 = acc[mt][2][r], v3 = acc[mt][3][r];
      float mn = fmaxf(fmaxf(v0, v1), fmaxf(v2, v3));
      mv[mt][r] = mn;
      lv[mt][r] = __expf(v0 - mn) + __expf(v1 - mn) + __expf(v2 - mn) + __expf(v3 - mn);
    }

  // merge across the 16 lanes sharing rows (different column subsets)
#pragma unroll
  for (int mask = 1; mask < 16; mask <<= 1)
#pragma unroll
    for (int mt = 0; mt < 4; ++mt)
#pragma unroll
      for (int r = 0; r < 4; ++r) {
        float om = __shfl_xor(mv[mt][r], mask, 64);
        float ol = __shfl_xor(lv[mt][r], mask, 64);
        float mn = fmaxf(mv[mt][r], om);
        lv[mt][r] = lv[mt][r] * __expf(mv[mt][r] - mn) + ol * __expf(om - mn);
        mv[mt][r] = mn;
      }

  // combine the two column-half waves via LDS (alias onto As4/Bs4 — done with tiles)
  float* cm = reinterpret_cast<float*>(As4);   // [2][BM]
  float* cl = reinterpret_cast<float*>(Bs4);   // [2][BM]
  __syncthreads();
  if (l15 == 0) {
#pragma unroll
    for (int mt = 0; mt < 4; ++mt)
#pragma unroll
      for (int r = 0; r < 4; ++r) {
        int rl = wm * 64 + mt * 16 + l4 * 4 + r;
        cm[wn * BM + rl] = mv[mt][r];
        cl[wn * BM + rl] = lv[mt][r];
      }
  }
  __syncthreads();
  if (tid < BM) {
    float m0 = cm[tid], l0 = cl[tid];
    float m1 = cm[BM + tid], l1 = cl[BM + tid];
    float mn = fmaxf(m0, m1);
    float ll = l0 * __expf(m0 - mn) + l1 * __expf(m1 - mn);
    size_t g = (size_t)(rb * BM + tid) * NPART + cp;
    pm[g] = mn;
    pl[g] = ll;
  }
}

// ---------------- loss: combine 64 partitions, subtract diag, atomic mean ----------------
__global__ void loss_kernel(const float* __restrict__ pm, const float* __restrict__ pl,
                            const float* __restrict__ dg, float* __restrict__ out) {
  __shared__ float red[4];
  const int tid = threadIdx.x;
  const int r   = blockIdx.x * 256 + tid;

  const float4* pmr = reinterpret_cast<const float4*>(pm + (size_t)r * NPART);
  const float4* plr = reinterpret_cast<const float4*>(pl + (size_t)r * NPART);

  float m = -1e30f, l = 0.f;
#pragma unroll
  for (int q = 0; q < NPART / 4; ++q) {
    float4 mv = pmr[q];
    float4 lv = plr[q];
#pragma unroll
    for (int k = 0; k < 4; ++k) {
      float m2 = (&mv.x)[k], l2 = (&lv.x)[k];
      float mn = fmaxf(m, m2);
      l = l * __expf(m - mn) + l2 * __expf(m2 - mn);
      m = mn;
    }
  }
  float local = m + __logf(l) - dg[r];

#pragma unroll
  for (int off = 32; off; off >>= 1) local += __shfl_xor(local, off, 64);
  if ((tid & 63) == 0) red[tid >> 6] = local;
  __syncthreads();
  if (tid == 0) {
    float s = red[0] + red[1] + red[2] + red[3];
    atomicAdd(out, s / (float)BS);
  }
}

extern "C" void kernel_launch(void* const* d_in, const int* in_sizes, int n_in,
                              void* d_out, int out_size, void* d_ws, size_t ws_size,
                              hipStream_t stream) {
  const float* nl = (const float*)d_in[0];
  const float* cd = (const float*)d_in[1];
  float* out = (float*)d_out;

  unsigned char* nl8 = (unsigned char*)d_ws;         // NEL fp8
  unsigned char* cd8 = nl8 + NEL;                    // NEL fp8
  float* pm = (float*)(cd8 + NEL);                   // BS*NPART
  float* pl = pm + (size_t)BS * NPART;               // BS*NPART
  float* dg = pl + (size_t)BS * NPART;               // BS

  // out = [loss, code_vec copy, nl_vec copy]; copies + out[0]=0 done in gemm prologue
  prep_kernel<<<BS / 4, 256, 0, stream>>>(nl, cd, nl8, cd8, dg);
  gemm_lse_kernel<<<dim3(NPART, BS / BM), 256, 0, stream>>>(nl8, cd8, cd, nl, out, pm, pl);
  loss_kernel<<<BS / 256, 256, 0, stream>>>(pm, pl, dg, out);
}

// Round 8
// 229.822 us; speedup vs baseline: 1.1394x; 1.0057x over previous
//
#include <hip/hip_runtime.h>

#define BS     8192
#define DIM    768
#define NPART  64               // 128-column partitions
#define BM     128
#define BN     128
#define BKB    128              // K-tile in fp8 bytes
#define NKT    (DIM / BKB)      // 6 k-tiles
#define NEL    ((size_t)BS * DIM)        // 6291456
#define NEL4   (NEL / 4)                 // 1572864 float4 tiles per input
#define CTILE  (2 * NEL4 - 1)            // dst float4 tiles: m in [1, 3145727]
#define SCL1   0x7F7F7F7F                // e8m0 = 127 -> scale 1.0 in every byte

typedef float facc_t __attribute__((ext_vector_type(4)));
typedef int   iv4    __attribute__((ext_vector_type(4)));
typedef int   iv8    __attribute__((ext_vector_type(8)));

typedef const __attribute__((address_space(1))) void gv_t;
typedef __attribute__((address_space(3))) void lv_t;

__device__ __forceinline__ void gll16(const void* g, void* l) {
  // async global->LDS DMA, 16B/lane; LDS dest = wave-uniform base + lane*16
  __builtin_amdgcn_global_load_lds((gv_t*)g, (lv_t*)l, 16, 0, 0);
}

// 8xi32 MFMA operand = concat of two 16B LDS vector loads.
// shufflevector concat is the canonical IR pattern -> 2x ds_read_b128, no alloca.
__device__ __forceinline__ iv8 ld_frag(const iv4* base, int lo, int hi) {
  iv4 a = base[lo];
  iv4 b = base[hi];
  return __builtin_shufflevector(a, b, 0, 1, 2, 3, 4, 5, 6, 7);
}

// pack float4 -> 4x fp8 e4m3 (OCP on gfx950)
__device__ __forceinline__ int pk_fp8(float4 v) {
  int w = __builtin_amdgcn_cvt_pk_fp8_f32(v.x, v.y, 0, false);
  w = __builtin_amdgcn_cvt_pk_fp8_f32(v.z, v.w, w, true);
  return w;
}

// ---------------- prep: fp8 convert (both inputs) + fp32 diag ----------------
__global__ void prep_kernel(const float* __restrict__ nl, const float* __restrict__ cd,
                            unsigned char* __restrict__ nl8, unsigned char* __restrict__ cd8,
                            float* __restrict__ dg) {
  const int lane = threadIdx.x & 63;
  const int wave = threadIdx.x >> 6;
  const int row  = blockIdx.x * 4 + wave;
  const size_t rbase = (size_t)row * DIM;
  const float4* ar = reinterpret_cast<const float4*>(nl + rbase);
  const float4* br = reinterpret_cast<const float4*>(cd + rbase);
  int* ba = reinterpret_cast<int*>(nl8 + rbase);   // 4 fp8 per int
  int* bb = reinterpret_cast<int*>(cd8 + rbase);

  float s = 0.f;
#pragma unroll
  for (int i = 0; i < 3; ++i) {                 // 192 float4 per row, 3 per lane
    int idx = lane + 64 * i;
    float4 x = ar[idx];
    float4 y = br[idx];
    ba[idx] = pk_fp8(x);
    bb[idx] = pk_fp8(y);
    s += x.x * y.x + x.y * y.y + x.z * y.z + x.w * y.w;
  }
#pragma unroll
  for (int off = 32; off; off >>= 1) s += __shfl_xor(s, off, 64);
  if (lane == 0) dg[row] = s;
}

// concat source: tile i of [cd | nl] as float4
__device__ __forceinline__ float4 cc4(const float4* cd4, const float4* nl4, size_t i) {
  return (i < NEL4) ? cd4[i] : nl4[i - NEL4];
}

// ---------------- fused GEMM (MX-fp8 MFMA, scales=1) + lse + output copy ----------------
// block: 256 threads (4 waves, 2x2 of 64x64), tile 128x128, one col-partition per block.
// grid: (NPART, BS/BM) = (64, 64) = 4096 blocks.
// LDS iv4-typed, XOR-swizzled: 16B unit at position p of row r holds logical unit p^(r&7).
__global__ __launch_bounds__(256, 4) void gemm_lse_kernel(
    const unsigned char* __restrict__ A8,
    const unsigned char* __restrict__ B8,
    const float* __restrict__ cdf, const float* __restrict__ nlf,
    float* __restrict__ outp,
    float* __restrict__ pm, float* __restrict__ pl) {
  __shared__ iv4 As4[BM * 8];   // 16 KB, 8 units of 16B per 128B row
  __shared__ iv4 Bs4[BN * 8];   // 16 KB

  const int tid  = threadIdx.x;
  const int lane = tid & 63;
  const int wave = tid >> 6;
  const int wm   = wave >> 1;
  const int wn   = wave & 1;
  const int l15  = lane & 15;
  const int l4   = lane >> 4;
  const int sw   = l15 & 7;        // row-dependent xor for fragment reads
  const int kb2  = l4 * 2;         // lane's first 16B logical unit (32B k-block)
  const int cp   = blockIdx.x;
  const int rb   = blockIdx.y;

  // ---- output copy prologue (dst 16B-aligned; out[4m..4m+3] = concat[4m-1..4m+2]) ----
  {
    const float4* cd4 = reinterpret_cast<const float4*>(cdf);
    const float4* nl4 = reinterpret_cast<const float4*>(nlf);
    const size_t gtid = ((size_t)blockIdx.y * gridDim.x + blockIdx.x) * blockDim.x + tid;
    const size_t nthr = (size_t)gridDim.x * gridDim.y * blockDim.x;   // 1048576
    for (size_t m = 1 + gtid; m <= CTILE; m += nthr) {
      float4 A = cc4(cd4, nl4, m - 1);
      float4 B = cc4(cd4, nl4, m);
      float4 d;
      d.x = A.w; d.y = B.x; d.z = B.y; d.w = B.z;
      *reinterpret_cast<float4*>(outp + 4 * m) = d;
    }
    if (gtid == 0) {
      outp[0] = 0.f;                       // loss accumulator (loss kernel atomically adds)
      outp[1] = cdf[0]; outp[2] = cdf[1]; outp[3] = cdf[2];
      outp[2 * NEL] = nlf[NEL - 1];        // last element
    }
  }

  // staging geometry (kt-invariant): unit u = wave*256 + t*64 + lane, 8 units/row
  int srow[4], sc8g[4];
#pragma unroll
  for (int t = 0; t < 4; ++t) {
    int u   = wave * 256 + t * 64 + lane;
    srow[t] = u >> 3;
    sc8g[t] = (u & 7) ^ (srow[t] & 7);
  }

  facc_t acc[4][4];
#pragma unroll
  for (int mt = 0; mt < 4; ++mt)
#pragma unroll
    for (int nt = 0; nt < 4; ++nt) acc[mt][nt] = (facc_t){0.f, 0.f, 0.f, 0.f};

  for (int kt = 0; kt < NKT; ++kt) {
    __syncthreads();
#pragma unroll
    for (int t = 0; t < 4; ++t) {
      int ub = (wave * 256 + t * 64) * 16;   // LDS byte base (lane adds lane*16)
      gll16(A8 + (size_t)(rb * BM + srow[t]) * DIM + kt * BKB + sc8g[t] * 16,
            reinterpret_cast<char*>(As4) + ub);
      gll16(B8 + (size_t)(cp * BN + srow[t]) * DIM + kt * BKB + sc8g[t] * 16,
            reinterpret_cast<char*>(Bs4) + ub);
    }
    __syncthreads();

    const int lo = kb2 ^ sw, hi = (kb2 + 1) ^ sw;
    // cache A fragments (32 VGPRs), stream B fragments one at a time (8 VGPRs)
    iv8 af[4];
#pragma unroll
    for (int mt = 0; mt < 4; ++mt)
      af[mt] = ld_frag(&As4[(wm * 64 + mt * 16 + l15) * 8], lo, hi);
#pragma unroll
    for (int nt = 0; nt < 4; ++nt) {
      iv8 bf = ld_frag(&Bs4[(wn * 64 + nt * 16 + l15) * 8], lo, hi);
#pragma unroll
      for (int mt = 0; mt < 4; ++mt)
        acc[mt][nt] = __builtin_amdgcn_mfma_scale_f32_16x16x128_f8f6f4(
            af[mt], bf, acc[mt][nt], 0, 0, 0, SCL1, 0, SCL1);
    }
  }

  // ---- lse over this block's 128 columns (one col-slice: no running state) ----
  float mv[4][4], lv[4][4];
#pragma unroll
  for (int mt = 0; mt < 4; ++mt)
#pragma unroll
    for (int r = 0; r < 4; ++r) {
      float v0 = acc[mt][0][r], v1 = acc[mt][1][r], v2 = acc[mt][2][r], v3 = acc[mt][3][r];
      float mn = fmaxf(fmaxf(v0, v1), fmaxf(v2, v3));
      mv[mt][r] = mn;
      lv[mt][r] = __expf(v0 - mn) + __expf(v1 - mn) + __expf(v2 - mn) + __expf(v3 - mn);
    }

  // merge across the 16 lanes sharing rows (different column subsets)
#pragma unroll
  for (int mask = 1; mask < 16; mask <<= 1)
#pragma unroll
    for (int mt = 0; mt < 4; ++mt)
#pragma unroll
      for (int r = 0; r < 4; ++r) {
        float om = __shfl_xor(mv[mt][r], mask, 64);
        float ol = __shfl_xor(lv[mt][r], mask, 64);
        float mn = fmaxf(mv[mt][r], om);
        lv[mt][r] = lv[mt][r] * __expf(mv[mt][r] - mn) + ol * __expf(om - mn);
        mv[mt][r] = mn;
      }

  // combine the two column-half waves via LDS (alias onto As4/Bs4 — done with tiles)
  float* cm = reinterpret_cast<float*>(As4);   // [2][BM]
  float* cl = reinterpret_cast<float*>(Bs4);   // [2][BM]
  __syncthreads();
  if (l15 == 0) {
#pragma unroll
    for (int mt = 0; mt < 4; ++mt)
#pragma unroll
      for (int r = 0; r < 4; ++r) {
        int rl = wm * 64 + mt * 16 + l4 * 4 + r;
        cm[wn * BM + rl] = mv[mt][r];
        cl[wn * BM + rl] = lv[mt][r];
      }
  }
  __syncthreads();
  if (tid < BM) {
    float m0 = cm[tid], l0 = cl[tid];
    float m1 = cm[BM + tid], l1 = cl[BM + tid];
    float mn = fmaxf(m0, m1);
    float ll = l0 * __expf(m0 - mn) + l1 * __expf(m1 - mn);
    size_t g = (size_t)(rb * BM + tid) * NPART + cp;
    pm[g] = mn;
    pl[g] = ll;
  }
}

// ---------------- loss: combine 64 partitions, subtract diag, atomic mean ----------------
__global__ void loss_kernel(const float* __restrict__ pm, const float* __restrict__ pl,
                            const float* __restrict__ dg, float* __restrict__ out) {
  __shared__ float red[4];
  const int tid = threadIdx.x;
  const int r   = blockIdx.x * 256 + tid;

  const float4* pmr = reinterpret_cast<const float4*>(pm + (size_t)r * NPART);
  const float4* plr = reinterpret_cast<const float4*>(pl + (size_t)r * NPART);

  float m = -1e30f, l = 0.f;
#pragma unroll
  for (int q = 0; q < NPART / 4; ++q) {
    float4 mv = pmr[q];
    float4 lv = plr[q];
#pragma unroll
    for (int k = 0; k < 4; ++k) {
      float m2 = (&mv.x)[k], l2 = (&lv.x)[k];
      float mn = fmaxf(m, m2);
      l = l * __expf(m - mn) + l2 * __expf(m2 - mn);
      m = mn;
    }
  }
  float local = m + __logf(l) - dg[r];

#pragma unroll
  for (int off = 32; off; off >>= 1) local += __shfl_xor(local, off, 64);
  if ((tid & 63) == 0) red[tid >> 6] = local;
  __syncthreads();
  if (tid == 0) {
    float s = red[0] + red[1] + red[2] + red[3];
    atomicAdd(out, s / (float)BS);
  }
}

extern "C" void kernel_launch(void* const* d_in, const int* in_sizes, int n_in,
                              void* d_out, int out_size, void* d_ws, size_t ws_size,
                              hipStream_t stream) {
  const float* nl = (const float*)d_in[0];
  const float* cd = (const float*)d_in[1];
  float* out = (float*)d_out;

  unsigned char* nl8 = (unsigned char*)d_ws;         // NEL fp8
  unsigned char* cd8 = nl8 + NEL;                    // NEL fp8
  float* pm = (float*)(cd8 + NEL);                   // BS*NPART
  float* pl = pm + (size_t)BS * NPART;               // BS*NPART
  float* dg = pl + (size_t)BS * NPART;               // BS

  // out = [loss, code_vec copy, nl_vec copy]; copies + out[0]=0 done in gemm prologue
  prep_kernel<<<BS / 4, 256, 0, stream>>>(nl, cd, nl8, cd8, dg);
  gemm_lse_kernel<<<dim3(NPART, BS / BM), 256, 0, stream>>>(nl8, cd8, cd, nl, out, pm, pl);
  loss_kernel<<<BS / 256, 256, 0, stream>>>(pm, pl, dg, out);
}